// Round 1
// baseline (202.570 us; speedup 1.0000x reference)
//
#include <hip/hip_runtime.h>

// Problem constants (fixed-shape bench)
#define B_ 4
#define K_ 64
#define R_ 16
#define H_ 16
#define S_ 2048
#define ROWS_PER_BLOCK 16

// ---------------------------------------------------------------------------
// Kernel A: one block per batch b.
//  anchor[b,h,j] = (1/K) * sum_i sum_r adj[b,i,j,r] * W[r,h]
//  colval[b,h,c] = 0, then colval[b,h,idx[b,k]] = anchor[b,h,k]  (k ascending
//  => last-write-wins on duplicate indices, matching numpy fancy assignment)
// ---------------------------------------------------------------------------
__global__ __launch_bounds__(256) void compute_colval_kernel(
    const float* __restrict__ adj,     // [B,K,K,R]
    const float* __restrict__ W,       // [R,H]
    const int*   __restrict__ idx,     // [B,K]
    float*       __restrict__ colval)  // [B,H,S]
{
    __shared__ float s_jr[K_ * R_];      // s[j][r] = sum_i adj[b,i,j,r]
    __shared__ float s_anchor[H_ * K_];  // anchor[h][j]
    __shared__ float s_W[R_ * H_];

    const int b   = blockIdx.x;
    const int tid = threadIdx.x;

    // Load W into LDS (R*H = 256 floats).
    if (tid < R_ * H_) s_W[tid] = W[tid];

    // Zero this batch's colval slab: H*S = 32768 floats -> 8192 float4.
    float4* cv4 = reinterpret_cast<float4*>(colval + (size_t)b * H_ * S_);
    #pragma unroll
    for (int i = tid; i < (H_ * S_) / 4; i += 256) {
        cv4[i] = make_float4(0.f, 0.f, 0.f, 0.f);
    }

    // s[j][r] = sum_i adj[b,i,j,r]. (j,r) flattened = 1024 entries; each
    // thread owns 4. Inner loop over i reads contiguous 1024-float rows.
    const float* adjb = adj + (size_t)b * K_ * K_ * R_;
    float acc0 = 0.f, acc1 = 0.f, acc2 = 0.f, acc3 = 0.f;
    for (int i = 0; i < K_; ++i) {
        const float* row = adjb + i * (K_ * R_);
        acc0 += row[tid];
        acc1 += row[tid + 256];
        acc2 += row[tid + 512];
        acc3 += row[tid + 768];
    }
    s_jr[tid]       = acc0;
    s_jr[tid + 256] = acc1;
    s_jr[tid + 512] = acc2;
    s_jr[tid + 768] = acc3;
    __syncthreads();

    // anchor[h][j] = (1/K) * sum_r s[j][r] * W[r][h]
    for (int p = tid; p < H_ * K_; p += 256) {
        const int h = p >> 6;   // p / K_
        const int j = p & 63;   // p % K_
        float a = 0.f;
        #pragma unroll
        for (int r = 0; r < R_; ++r)
            a += s_jr[j * R_ + r] * s_W[r * H_ + h];
        s_anchor[p] = a * (1.0f / K_);
    }
    __syncthreads();

    // Scatter, serial ascending k per head => last-write-wins for duplicates.
    if (tid < H_) {
        const int h = tid;
        float* cvh = colval + ((size_t)b * H_ + h) * S_;
        for (int k = 0; k < K_; ++k) {
            const int c = idx[b * K_ + k];
            cvh[c] = s_anchor[h * K_ + k];
        }
    }
}

// ---------------------------------------------------------------------------
// Kernel B: streaming broadcast. Block (x=row-chunk, y=bh). Each block loads
// its 8 KB colval row once (2 float4/thread) and writes ROWS_PER_BLOCK rows.
// ---------------------------------------------------------------------------
__global__ __launch_bounds__(256) void broadcast_rows_kernel(
    const float4* __restrict__ colval4,  // [B*H, S/4]
    float4*       __restrict__ out4)     // [B*H, S, S/4]
{
    const int bh   = blockIdx.y;
    const int row0 = blockIdx.x * ROWS_PER_BLOCK;
    const int t    = threadIdx.x;

    const int cvbase = bh * (S_ / 4);            // S/4 = 512
    const float4 v0 = colval4[cvbase + t];
    const float4 v1 = colval4[cvbase + 256 + t];

    float4* base = out4 + ((size_t)bh * S_ + row0) * (S_ / 4);
    #pragma unroll
    for (int r = 0; r < ROWS_PER_BLOCK; ++r) {
        base[(size_t)r * (S_ / 4) + t]       = v0;
        base[(size_t)r * (S_ / 4) + 256 + t] = v1;
    }
}

extern "C" void kernel_launch(void* const* d_in, const int* in_sizes, int n_in,
                              void* d_out, int out_size, void* d_ws, size_t ws_size,
                              hipStream_t stream) {
    const float* adj = (const float*)d_in[0];   // [B,K,K,R] fp32
    const float* W   = (const float*)d_in[1];   // [R,H] fp32
    const int*   idx = (const int*)d_in[2];     // [B,K] int32
    // d_in[3] = seq_l scalar (2048), hardcoded as S_.

    float* out    = (float*)d_out;
    float* colval = (float*)d_ws;               // B*H*S fp32 = 512 KB scratch

    compute_colval_kernel<<<B_, 256, 0, stream>>>(adj, W, idx, colval);

    dim3 grid(S_ / ROWS_PER_BLOCK, B_ * H_);    // (128, 64) = 8192 blocks
    broadcast_rows_kernel<<<grid, 256, 0, stream>>>(
        (const float4*)colval, (float4*)out);
}